// Round 12
// baseline (1053.492 us; speedup 1.0000x reference)
//
#include <hip/hip_runtime.h>
#include <math.h>

#define N_NODES 16384
#define N_EDGES 524288
#define N_GRAPHS 64
#define HID 128
#define FILT 128
#define NG 51
#define NL 6
#define TROWS 2048   // filter-table resolution
#define DMAX 8.66025404f          // 5*sqrt(3), max possible distance
#define DSTEP (DMAX / (TROWS - 1))
#define INV_DSTEP ((TROWS - 1) / DMAX)
#define EU 2         // edge-pair unroll (4 edges in flight)
#define NDT 32       // node tile for node GEMMs
#define NDP 33       // padded stride

__device__ __forceinline__ float ssp(float x) {
    float sp = (x > 20.0f) ? x : log1pf(__expf(x));
    return sp - 0.6931471805599453f;
}

__global__ void k_embed(const int* __restrict__ z, const float* __restrict__ emb,
                        float* __restrict__ h) {
    int i = blockIdx.x * blockDim.x + threadIdx.x;
    int n = i >> 7, c = i & 127;
    h[i] = emb[z[n] * HID + c];
}

__global__ void k_hist(const int* __restrict__ ei, int* __restrict__ cnt) {
    int e = blockIdx.x * blockDim.x + threadIdx.x;
    if (e < N_EDGES) atomicAdd(&cnt[ei[e]], 1);
}

__global__ __launch_bounds__(1024) void k_scan(const int* __restrict__ cnt,
                                               int* __restrict__ rowptr,
                                               int* __restrict__ wo) {
    __shared__ int sums[1024];
    int t = threadIdx.x;
    int loc[16];
    int s = 0;
    #pragma unroll
    for (int i = 0; i < 16; ++i) { loc[i] = cnt[t * 16 + i]; s += loc[i]; }
    sums[t] = s;
    __syncthreads();
    for (int off = 1; off < 1024; off <<= 1) {
        int v = sums[t];
        int u = (t >= off) ? sums[t - off] : 0;
        __syncthreads();
        sums[t] = v + u;
        __syncthreads();
    }
    int ex = sums[t] - s;
    #pragma unroll
    for (int i = 0; i < 16; ++i) {
        rowptr[t * 16 + i] = ex;
        wo[t * 16 + i] = ex;
        ex += loc[i];
    }
    if (t == 1023) rowptr[16384] = ex;
}

// scatter into CSR order: meta.x = col, meta.y = ew bits
__global__ void k_scatter(const int* __restrict__ ei, const float* __restrict__ pos,
                          int* __restrict__ wo, int2* __restrict__ meta) {
    int e = blockIdx.x * blockDim.x + threadIdx.x;
    if (e >= N_EDGES) return;
    int r = ei[e], c = ei[N_EDGES + e];
    int p = atomicAdd(&wo[r], 1);
    float dx = pos[r * 3 + 0] - pos[c * 3 + 0];
    float dy = pos[r * 3 + 1] - pos[c * 3 + 1];
    float dz = pos[r * 3 + 2] - pos[c * 3 + 2];
    float ew = sqrtf(dx * dx + dy * dy + dz * dz);
    meta[p] = make_int2(c, __float_as_int(ew));
}

// Filter tables (flat [TROWS][FILT], includes cosine cutoff)
__global__ __launch_bounds__(512) void k_tab(
    const float* __restrict__ mlp1_w, const float* __restrict__ mlp1_b,
    const float* __restrict__ mlp2_w, const float* __restrict__ mlp2_b,
    float* __restrict__ ftab)
{
    const int layer = blockIdx.x >> 5;
    const int tile  = blockIdx.x & 31;
    const float* W1 = mlp1_w + (size_t)layer * NG * FILT;
    const float* B1 = mlp1_b + (size_t)layer * FILT;
    const float* W2 = mlp2_w + (size_t)layer * FILT * FILT;
    const float* B2 = mlp2_b + (size_t)layer * FILT;
    float* out = ftab + (size_t)layer * TROWS * FILT + (size_t)tile * 64 * FILT;
    __shared__ float buf[FILT * 64];
    const int tid = threadIdx.x;
    const int e0 = (tid & 15) * 4;
    const int c0 = (tid >> 4) * 4;
    for (int idx = tid; idx < NG * 64; idx += 512) {
        int k = idx >> 6, e = idx & 63;
        float d = (float)(tile * 64 + e) * DSTEP;
        float dd = d - 0.2f * (float)k;
        buf[idx] = __expf(-12.5f * dd * dd);
    }
    __syncthreads();
    float acc[4][4];
    #pragma unroll
    for (int i = 0; i < 4; ++i)
        #pragma unroll
        for (int j = 0; j < 4; ++j) acc[i][j] = B1[c0 + j];
    for (int k = 0; k < NG; ++k) {
        float4 a = *(float4*)&buf[k * 64 + e0];
        float4 b = *(const float4*)&W1[k * FILT + c0];
        #pragma unroll
        for (int i = 0; i < 4; ++i)
            #pragma unroll
            for (int j = 0; j < 4; ++j)
                acc[i][j] += ((float*)&a)[i] * ((float*)&b)[j];
    }
    __syncthreads();
    #pragma unroll
    for (int j = 0; j < 4; ++j) {
        float4 w;
        ((float*)&w)[0] = ssp(acc[0][j]);
        ((float*)&w)[1] = ssp(acc[1][j]);
        ((float*)&w)[2] = ssp(acc[2][j]);
        ((float*)&w)[3] = ssp(acc[3][j]);
        *(float4*)&buf[(c0 + j) * 64 + e0] = w;
    }
    __syncthreads();
    float acc2[4][4];
    #pragma unroll
    for (int i = 0; i < 4; ++i)
        #pragma unroll
        for (int j = 0; j < 4; ++j) acc2[i][j] = B2[c0 + j];
    for (int k = 0; k < FILT; ++k) {
        float4 a = *(float4*)&buf[k * 64 + e0];
        float4 b = *(const float4*)&W2[k * FILT + c0];
        #pragma unroll
        for (int i = 0; i < 4; ++i)
            #pragma unroll
            for (int j = 0; j < 4; ++j)
                acc2[i][j] += ((float*)&a)[i] * ((float*)&b)[j];
    }
    #pragma unroll
    for (int i = 0; i < 4; ++i) {
        int r = tile * 64 + e0 + i;
        float d = (float)r * DSTEP;
        float C = 0.5f * (__cosf(d * 0.31415926535f) + 1.0f);
        #pragma unroll
        for (int j = 0; j < 4; ++j)
            out[(e0 + i) * FILT + c0 + j] = acc2[i][j] * C;
    }
}

// Half-wave-paired edge aggregation (unchanged from R10/R11 winner).
__global__ __launch_bounds__(256, 8) void k_edge6(
    const int2* __restrict__ meta, const int* __restrict__ rowptr,
    const float* __restrict__ xh, const float* __restrict__ tab,
    float* __restrict__ agg)
{
    const int row = blockIdx.x * 4 + (threadIdx.x >> 6);
    const int lane = threadIdx.x & 63;
    const int half = lane >> 5;
    const int c4 = (lane & 31) * 4;
    const int es = rowptr[row], ee = rowptr[row + 1];
    float4 acc = make_float4(0.f, 0.f, 0.f, 0.f);
    if (es < ee) {
        int2 mcur[EU];
        #pragma unroll
        for (int u = 0; u < EU; ++u)
            mcur[u] = meta[min(es + 2 * u + half, ee - 1)];
        for (int e = es; e < ee; e += 2 * EU) {
            const int en = e + 2 * EU;
            int2 mnext[EU];
            if (en < ee) {
                #pragma unroll
                for (int u = 0; u < EU; ++u)
                    mnext[u] = meta[min(en + 2 * u + half, ee - 1)];
            }
            float4 t0[EU], t1[EU], xv[EU];
            float f[EU], sc[EU];
            #pragma unroll
            for (int u = 0; u < EU; ++u) {
                sc[u] = (e + 2 * u + half < ee) ? 1.f : 0.f;
                float d = __int_as_float(mcur[u].y);
                float uu = d * INV_DSTEP;
                int i0 = min((int)uu, TROWS - 2);
                f[u] = uu - (float)i0;
                t0[u] = *(const float4*)&tab[(size_t)i0 * FILT + c4];
                t1[u] = *(const float4*)&tab[(size_t)(i0 + 1) * FILT + c4];
                xv[u] = *(const float4*)&xh[(size_t)mcur[u].x * FILT + c4];
            }
            #pragma unroll
            for (int u = 0; u < EU; ++u) {
                acc.x = fmaf(fmaf(f[u], t1[u].x - t0[u].x, t0[u].x) * sc[u], xv[u].x, acc.x);
                acc.y = fmaf(fmaf(f[u], t1[u].y - t0[u].y, t0[u].y) * sc[u], xv[u].y, acc.y);
                acc.z = fmaf(fmaf(f[u], t1[u].z - t0[u].z, t0[u].z) * sc[u], xv[u].z, acc.z);
                acc.w = fmaf(fmaf(f[u], t1[u].w - t0[u].w, t0[u].w) * sc[u], xv[u].w, acc.w);
            }
            #pragma unroll
            for (int u = 0; u < EU; ++u) mcur[u] = mnext[u];
        }
        acc.x += __shfl_xor(acc.x, 32, 64);
        acc.y += __shfl_xor(acc.y, 32, 64);
        acc.z += __shfl_xor(acc.z, 32, 64);
        acc.w += __shfl_xor(acc.w, 32, 64);
    }
    if (half == 0)
        *(float4*)&agg[(size_t)row * FILT + c4] = acc;
}

// ---------------------------------------------------------------------------
// Node GEMMs, 32-node tiles: 512 threads = 8 waves, grid 512 -> 2 blocks/CU.
// ch0 = wave*8 + (lane>>5)*64 -- lane-dependent => weights go through VECTOR
// global loads (vmcnt), decoupled from the LDS reads (lgkmcnt). Lanes i and
// i+32 read the same LDS word (broadcast). Single 16.9 KB buffer reused
// across GEMM stages.
// ---------------------------------------------------------------------------
__device__ __forceinline__ void stage32(const float* __restrict__ X, int n0,
                                        float* __restrict__ buf, int tid) {
    #pragma unroll
    for (int it = 0; it < 2; ++it) {
        int fi = tid + it * 512;
        int node = fi & 31, kq = fi >> 5;   // kq 0..31
        float4 v = *(const float4*)&X[(size_t)(n0 + node) * 128 + kq * 4];
        buf[(4 * kq + 0) * NDP + node] = v.x;
        buf[(4 * kq + 1) * NDP + node] = v.y;
        buf[(4 * kq + 2) * NDP + node] = v.z;
        buf[(4 * kq + 3) * NDP + node] = v.w;
    }
}

__device__ __forceinline__ void gemm32(const float* __restrict__ buf, int node,
                                       const float* __restrict__ W, int ch0,
                                       float* acc) {
    #pragma unroll 8
    for (int k = 0; k < 128; ++k) {
        float a = buf[k * NDP + node];
        float4 w0 = *(const float4*)&W[k * 128 + ch0];
        float4 w1 = *(const float4*)&W[k * 128 + ch0 + 4];
        acc[0] = fmaf(a, w0.x, acc[0]); acc[1] = fmaf(a, w0.y, acc[1]);
        acc[2] = fmaf(a, w0.z, acc[2]); acc[3] = fmaf(a, w0.w, acc[3]);
        acc[4] = fmaf(a, w1.x, acc[4]); acc[5] = fmaf(a, w1.y, acc[5]);
        acc[6] = fmaf(a, w1.z, acc[6]); acc[7] = fmaf(a, w1.w, acc[7]);
    }
}

__global__ __launch_bounds__(512, 4) void k_gemm0(const float* __restrict__ X,
                                                  const float* __restrict__ W,
                                                  float* __restrict__ Y) {
    __shared__ float buf[128 * NDP];
    const int tid = threadIdx.x;
    const int node = tid & 31;
    const int ch0 = (tid >> 6) * 8 + ((tid >> 5) & 1) * 64;
    const int n0 = blockIdx.x * NDT;
    stage32(X, n0, buf, tid);
    __syncthreads();
    float acc[8] = {0, 0, 0, 0, 0, 0, 0, 0};
    gemm32(buf, node, W, ch0, acc);
    size_t ro = (size_t)(n0 + node) * 128 + ch0;
    *(float4*)&Y[ro]     = make_float4(acc[0], acc[1], acc[2], acc[3]);
    *(float4*)&Y[ro + 4] = make_float4(acc[4], acc[5], acc[6], acc[7]);
}

template<bool RESID, bool G3>
__global__ __launch_bounds__(512, 4) void k_node3(
    const float* __restrict__ X,
    const float* __restrict__ W1, const float* __restrict__ B1,
    const float* __restrict__ W2, const float* __restrict__ B2,
    const float* __restrict__ Hin, float* __restrict__ Hout,
    const float* __restrict__ W3, float* __restrict__ XHout)
{
    __shared__ float buf[128 * NDP];
    const int tid = threadIdx.x;
    const int node = tid & 31;
    const int ch0 = (tid >> 6) * 8 + ((tid >> 5) & 1) * 64;
    const int n0 = blockIdx.x * NDT;
    stage32(X, n0, buf, tid);
    __syncthreads();
    // GEMM1 + bias + ssp
    float acc[8];
    #pragma unroll
    for (int j = 0; j < 8; ++j) acc[j] = B1[ch0 + j];
    gemm32(buf, node, W1, ch0, acc);
    __syncthreads();                          // all GEMM1 reads of buf done
    #pragma unroll
    for (int j = 0; j < 8; ++j)
        buf[(ch0 + j) * NDP + node] = ssp(acc[j]);
    __syncthreads();
    // GEMM2 + bias (+residual)
    float acc2[8];
    #pragma unroll
    for (int j = 0; j < 8; ++j) acc2[j] = B2[ch0 + j];
    gemm32(buf, node, W2, ch0, acc2);
    size_t ro = (size_t)(n0 + node) * 128 + ch0;
    if (RESID) {
        float4 h0 = *(const float4*)&Hin[ro];
        float4 h1 = *(const float4*)&Hin[ro + 4];
        acc2[0] += h0.x; acc2[1] += h0.y; acc2[2] += h0.z; acc2[3] += h0.w;
        acc2[4] += h1.x; acc2[5] += h1.y; acc2[6] += h1.z; acc2[7] += h1.w;
    }
    *(float4*)&Hout[ro]     = make_float4(acc2[0], acc2[1], acc2[2], acc2[3]);
    *(float4*)&Hout[ro + 4] = make_float4(acc2[4], acc2[5], acc2[6], acc2[7]);
    if (G3) {
        __syncthreads();                      // all GEMM2 reads done
        #pragma unroll
        for (int j = 0; j < 8; ++j)
            buf[(ch0 + j) * NDP + node] = acc2[j];
        __syncthreads();
        float acc3[8] = {0, 0, 0, 0, 0, 0, 0, 0};
        gemm32(buf, node, W3, ch0, acc3);
        *(float4*)&XHout[ro]     = make_float4(acc3[0], acc3[1], acc3[2], acc3[3]);
        *(float4*)&XHout[ro + 4] = make_float4(acc3[4], acc3[5], acc3[6], acc3[7]);
    }
}

// Partial-sum pooling using sortedness of batch.
__global__ __launch_bounds__(128) void k_pool2(const float* __restrict__ x,
                                               const int* __restrict__ batch,
                                               float* __restrict__ gsum) {
    const int c = threadIdx.x;
    const int n0 = blockIdx.x * 64;
    float acc = 0.f;
    int cur = batch[n0];
    for (int i = 0; i < 64; ++i) {
        int g = batch[n0 + i];
        float v = x[(size_t)(n0 + i) * 128 + c];
        if (g != cur) {
            atomicAdd(&gsum[cur * 128 + c], acc);
            acc = 0.f;
            cur = g;
        }
        acc += v;
    }
    atomicAdd(&gsum[cur * 128 + c], acc);
}

__global__ void k_div(const float* __restrict__ gsum, const int* __restrict__ batch,
                      float* __restrict__ out) {
    int g = blockIdx.x;
    int c = threadIdx.x;
    int a = 0, b = N_NODES;
    while (a < b) { int m = (a + b) >> 1; if (batch[m] < g) a = m + 1; else b = m; }
    int lo = a;
    b = N_NODES;
    while (a < b) { int m = (a + b) >> 1; if (batch[m] < g + 1) a = m + 1; else b = m; }
    int cnt = a - lo;
    out[g * 128 + c] = gsum[g * 128 + c] / fmaxf((float)cnt, 1.0f);
}

extern "C" void kernel_launch(void* const* d_in, const int* in_sizes, int n_in,
                              void* d_out, int out_size, void* d_ws, size_t ws_size,
                              hipStream_t stream) {
    const int*   z       = (const int*)  d_in[0];
    const float* pos     = (const float*)d_in[1];
    const int*   batch   = (const int*)  d_in[2];
    const int*   ei      = (const int*)  d_in[3];
    const float* emb     = (const float*)d_in[4];
    const float* mlp1_w  = (const float*)d_in[5];
    const float* mlp1_b  = (const float*)d_in[6];
    const float* mlp2_w  = (const float*)d_in[7];
    const float* mlp2_b  = (const float*)d_in[8];
    const float* cl1_w   = (const float*)d_in[9];
    const float* cl2_w   = (const float*)d_in[10];
    const float* cl2_b   = (const float*)d_in[11];
    const float* lin_w   = (const float*)d_in[12];
    const float* lin_b   = (const float*)d_in[13];
    const float* out1_w  = (const float*)d_in[14];
    const float* out1_b  = (const float*)d_in[15];
    const float* out2_w  = (const float*)d_in[16];
    const float* out2_b  = (const float*)d_in[17];

    float* ws     = (float*)d_ws;
    float* h      = ws;
    float* xh     = h    + (size_t)N_NODES * HID;
    float* agg    = xh   + (size_t)N_NODES * HID;
    int2*  meta   = (int2*)(agg + (size_t)N_NODES * HID);
    int*   cnt    = (int*)(meta + N_EDGES);
    int*   rowptr = cnt + N_NODES;
    int*   wo     = rowptr + N_NODES + 1;
    float* gsum   = (float*)(wo + N_NODES);            // 64*128
    float* ftab   = gsum + N_GRAPHS * 128;             // NL*TROWS*FILT floats

    hipMemsetAsync(cnt, 0, N_NODES * sizeof(int), stream);
    hipMemsetAsync(gsum, 0, N_GRAPHS * 128 * sizeof(float), stream);
    k_embed<<<N_NODES * HID / 256, 256, 0, stream>>>(z, emb, h);
    k_hist<<<N_EDGES / 256, 256, 0, stream>>>(ei, cnt);
    k_scan<<<1, 1024, 0, stream>>>(cnt, rowptr, wo);
    k_scatter<<<N_EDGES / 256, 256, 0, stream>>>(ei, pos, wo, meta);
    k_tab<<<NL * 32, 512, 0, stream>>>(mlp1_w, mlp1_b, mlp2_w, mlp2_b, ftab);

    k_gemm0<<<N_NODES / NDT, 512, 0, stream>>>(h, cl1_w, xh);
    for (int i = 0; i < NL; ++i) {
        k_edge6<<<N_NODES / 4, 256, 0, stream>>>(
            meta, rowptr, xh, ftab + (size_t)i * TROWS * FILT, agg);
        if (i < NL - 1) {
            k_node3<true, true><<<N_NODES / NDT, 512, 0, stream>>>(
                agg, cl2_w + (size_t)i * FILT * HID, cl2_b + (size_t)i * HID,
                lin_w + (size_t)i * HID * HID, lin_b + (size_t)i * HID,
                h, h, cl1_w + (size_t)(i + 1) * HID * FILT, xh);
        } else {
            k_node3<true, false><<<N_NODES / NDT, 512, 0, stream>>>(
                agg, cl2_w + (size_t)i * FILT * HID, cl2_b + (size_t)i * HID,
                lin_w + (size_t)i * HID * HID, lin_b + (size_t)i * HID,
                h, h, nullptr, nullptr);
        }
    }
    k_node3<false, false><<<N_NODES / NDT, 512, 0, stream>>>(
        h, out1_w, out1_b, out2_w, out2_b, nullptr, xh, nullptr, nullptr);
    k_pool2<<<N_NODES / 64, 128, 0, stream>>>(xh, batch, gsum);
    k_div<<<N_GRAPHS, 128, 0, stream>>>(gsum, batch, (float*)d_out);
}

// Round 13
// 629.590 us; speedup vs baseline: 1.6733x; 1.6733x over previous
//
#include <hip/hip_runtime.h>
#include <math.h>

#define N_NODES 16384
#define N_EDGES 524288
#define N_GRAPHS 64
#define HID 128
#define FILT 128
#define NG 51
#define NL 6
#define TROWS 2048   // filter-table resolution
#define DMAX 8.66025404f          // 5*sqrt(3), max possible distance
#define DSTEP (DMAX / (TROWS - 1))
#define INV_DSTEP ((TROWS - 1) / DMAX)
#define EU 2         // edge-pair unroll (4 edges in flight)
#define TSTRIDE 132  // LDS row stride for t-tile (pad; 132*4B, 8B-aligned)

__device__ __forceinline__ float ssp(float x) {
    float sp = (x > 20.0f) ? x : log1pf(__expf(x));
    return sp - 0.6931471805599453f;
}

__global__ void k_embed(const int* __restrict__ z, const float* __restrict__ emb,
                        float* __restrict__ h) {
    int i = blockIdx.x * blockDim.x + threadIdx.x;
    int n = i >> 7, c = i & 127;
    h[i] = emb[z[n] * HID + c];
}

__global__ void k_hist(const int* __restrict__ ei, int* __restrict__ cnt) {
    int e = blockIdx.x * blockDim.x + threadIdx.x;
    if (e < N_EDGES) atomicAdd(&cnt[ei[e]], 1);
}

__global__ __launch_bounds__(1024) void k_scan(const int* __restrict__ cnt,
                                               int* __restrict__ rowptr,
                                               int* __restrict__ wo) {
    __shared__ int sums[1024];
    int t = threadIdx.x;
    int loc[16];
    int s = 0;
    #pragma unroll
    for (int i = 0; i < 16; ++i) { loc[i] = cnt[t * 16 + i]; s += loc[i]; }
    sums[t] = s;
    __syncthreads();
    for (int off = 1; off < 1024; off <<= 1) {
        int v = sums[t];
        int u = (t >= off) ? sums[t - off] : 0;
        __syncthreads();
        sums[t] = v + u;
        __syncthreads();
    }
    int ex = sums[t] - s;
    #pragma unroll
    for (int i = 0; i < 16; ++i) {
        rowptr[t * 16 + i] = ex;
        wo[t * 16 + i] = ex;
        ex += loc[i];
    }
    if (t == 1023) rowptr[16384] = ex;
}

// scatter into CSR order: meta.x = col, meta.y = ew bits
__global__ void k_scatter(const int* __restrict__ ei, const float* __restrict__ pos,
                          int* __restrict__ wo, int2* __restrict__ meta) {
    int e = blockIdx.x * blockDim.x + threadIdx.x;
    if (e >= N_EDGES) return;
    int r = ei[e], c = ei[N_EDGES + e];
    int p = atomicAdd(&wo[r], 1);
    float dx = pos[r * 3 + 0] - pos[c * 3 + 0];
    float dy = pos[r * 3 + 1] - pos[c * 3 + 1];
    float dz = pos[r * 3 + 2] - pos[c * 3 + 2];
    float ew = sqrtf(dx * dx + dy * dy + dz * dz);
    meta[p] = make_int2(c, __float_as_int(ew));
}

// Filter tables (flat [TROWS][FILT], includes cosine cutoff)
__global__ __launch_bounds__(512) void k_tab(
    const float* __restrict__ mlp1_w, const float* __restrict__ mlp1_b,
    const float* __restrict__ mlp2_w, const float* __restrict__ mlp2_b,
    float* __restrict__ ftab)
{
    const int layer = blockIdx.x >> 5;
    const int tile  = blockIdx.x & 31;
    const float* W1 = mlp1_w + (size_t)layer * NG * FILT;
    const float* B1 = mlp1_b + (size_t)layer * FILT;
    const float* W2 = mlp2_w + (size_t)layer * FILT * FILT;
    const float* B2 = mlp2_b + (size_t)layer * FILT;
    float* out = ftab + (size_t)layer * TROWS * FILT + (size_t)tile * 64 * FILT;
    __shared__ float buf[FILT * 64];
    const int tid = threadIdx.x;
    const int e0 = (tid & 15) * 4;
    const int c0 = (tid >> 4) * 4;
    for (int idx = tid; idx < NG * 64; idx += 512) {
        int k = idx >> 6, e = idx & 63;
        float d = (float)(tile * 64 + e) * DSTEP;
        float dd = d - 0.2f * (float)k;
        buf[idx] = __expf(-12.5f * dd * dd);
    }
    __syncthreads();
    float acc[4][4];
    #pragma unroll
    for (int i = 0; i < 4; ++i)
        #pragma unroll
        for (int j = 0; j < 4; ++j) acc[i][j] = B1[c0 + j];
    for (int k = 0; k < NG; ++k) {
        float4 a = *(float4*)&buf[k * 64 + e0];
        float4 b = *(const float4*)&W1[k * FILT + c0];
        #pragma unroll
        for (int i = 0; i < 4; ++i)
            #pragma unroll
            for (int j = 0; j < 4; ++j)
                acc[i][j] += ((float*)&a)[i] * ((float*)&b)[j];
    }
    __syncthreads();
    #pragma unroll
    for (int j = 0; j < 4; ++j) {
        float4 w;
        ((float*)&w)[0] = ssp(acc[0][j]);
        ((float*)&w)[1] = ssp(acc[1][j]);
        ((float*)&w)[2] = ssp(acc[2][j]);
        ((float*)&w)[3] = ssp(acc[3][j]);
        *(float4*)&buf[(c0 + j) * 64 + e0] = w;
    }
    __syncthreads();
    float acc2[4][4];
    #pragma unroll
    for (int i = 0; i < 4; ++i)
        #pragma unroll
        for (int j = 0; j < 4; ++j) acc2[i][j] = B2[c0 + j];
    for (int k = 0; k < FILT; ++k) {
        float4 a = *(float4*)&buf[k * 64 + e0];
        float4 b = *(const float4*)&W2[k * FILT + c0];
        #pragma unroll
        for (int i = 0; i < 4; ++i)
            #pragma unroll
            for (int j = 0; j < 4; ++j)
                acc2[i][j] += ((float*)&a)[i] * ((float*)&b)[j];
    }
    #pragma unroll
    for (int i = 0; i < 4; ++i) {
        int r = tile * 64 + e0 + i;
        float d = (float)r * DSTEP;
        float C = 0.5f * (__cosf(d * 0.31415926535f) + 1.0f);
        #pragma unroll
        for (int j = 0; j < 4; ++j)
            out[(e0 + i) * FILT + c0 + j] = acc2[i][j] * C;
    }
}

// Half-wave-paired edge aggregation (unchanged from R11 winner).
__global__ __launch_bounds__(256, 8) void k_edge6(
    const int2* __restrict__ meta, const int* __restrict__ rowptr,
    const float* __restrict__ xh, const float* __restrict__ tab,
    float* __restrict__ agg)
{
    const int row = blockIdx.x * 4 + (threadIdx.x >> 6);
    const int lane = threadIdx.x & 63;
    const int half = lane >> 5;
    const int c4 = (lane & 31) * 4;
    const int es = rowptr[row], ee = rowptr[row + 1];
    float4 acc = make_float4(0.f, 0.f, 0.f, 0.f);
    if (es < ee) {
        int2 mcur[EU];
        #pragma unroll
        for (int u = 0; u < EU; ++u)
            mcur[u] = meta[min(es + 2 * u + half, ee - 1)];
        for (int e = es; e < ee; e += 2 * EU) {
            const int en = e + 2 * EU;
            int2 mnext[EU];
            if (en < ee) {
                #pragma unroll
                for (int u = 0; u < EU; ++u)
                    mnext[u] = meta[min(en + 2 * u + half, ee - 1)];
            }
            float4 t0[EU], t1[EU], xv[EU];
            float f[EU], sc[EU];
            #pragma unroll
            for (int u = 0; u < EU; ++u) {
                sc[u] = (e + 2 * u + half < ee) ? 1.f : 0.f;
                float d = __int_as_float(mcur[u].y);
                float uu = d * INV_DSTEP;
                int i0 = min((int)uu, TROWS - 2);
                f[u] = uu - (float)i0;
                t0[u] = *(const float4*)&tab[(size_t)i0 * FILT + c4];
                t1[u] = *(const float4*)&tab[(size_t)(i0 + 1) * FILT + c4];
                xv[u] = *(const float4*)&xh[(size_t)mcur[u].x * FILT + c4];
            }
            #pragma unroll
            for (int u = 0; u < EU; ++u) {
                acc.x = fmaf(fmaf(f[u], t1[u].x - t0[u].x, t0[u].x) * sc[u], xv[u].x, acc.x);
                acc.y = fmaf(fmaf(f[u], t1[u].y - t0[u].y, t0[u].y) * sc[u], xv[u].y, acc.y);
                acc.z = fmaf(fmaf(f[u], t1[u].z - t0[u].z, t0[u].z) * sc[u], xv[u].z, acc.z);
                acc.w = fmaf(fmaf(f[u], t1[u].w - t0[u].w, t0[u].w) * sc[u], xv[u].w, acc.w);
            }
            #pragma unroll
            for (int u = 0; u < EU; ++u) mcur[u] = mnext[u];
        }
        acc.x += __shfl_xor(acc.x, 32, 64);
        acc.y += __shfl_xor(acc.y, 32, 64);
        acc.z += __shfl_xor(acc.z, 32, 64);
        acc.w += __shfl_xor(acc.w, 32, 64);
    }
    if (half == 0)
        *(float4*)&agg[(size_t)row * FILT + c4] = acc;
}

// ---------------------------------------------------------------------------
// Node GEMMs, wave = 4 nodes x 128 channels (lane = channel).
// W: coalesced per-lane vector loads (vmcnt). A (GEMM1): wave-uniform row
// pointers via readfirstlane -> scalar s_loads, no ds ops in the loop.
// A (GEMM2/3): wave-private LDS tile, uniform-address broadcast ds_read_b64;
// W stays on vmcnt -> counters never mixed. Grid 1024 x 256 -> 4 blocks/CU.
// ---------------------------------------------------------------------------
__global__ __launch_bounds__(256, 4) void k_gemm0(const float* __restrict__ X,
                                                  const float* __restrict__ W,
                                                  float* __restrict__ Y) {
    const int w = threadIdx.x >> 6;
    const int lane = threadIdx.x & 63;
    const int nb = __builtin_amdgcn_readfirstlane(blockIdx.x * 16 + w * 4);
    const float* x0 = X + (size_t)nb * 128;
    const float* x1 = x0 + 128;
    const float* x2 = x1 + 128;
    const float* x3 = x2 + 128;
    float acc[4][2];
    #pragma unroll
    for (int j = 0; j < 4; ++j) { acc[j][0] = 0.f; acc[j][1] = 0.f; }
    #pragma unroll 8
    for (int k = 0; k < 128; ++k) {
        float wa = W[k * 128 + lane];
        float wb = W[k * 128 + lane + 64];
        float a0 = x0[k], a1 = x1[k], a2 = x2[k], a3 = x3[k];
        acc[0][0] = fmaf(a0, wa, acc[0][0]); acc[0][1] = fmaf(a0, wb, acc[0][1]);
        acc[1][0] = fmaf(a1, wa, acc[1][0]); acc[1][1] = fmaf(a1, wb, acc[1][1]);
        acc[2][0] = fmaf(a2, wa, acc[2][0]); acc[2][1] = fmaf(a2, wb, acc[2][1]);
        acc[3][0] = fmaf(a3, wa, acc[3][0]); acc[3][1] = fmaf(a3, wb, acc[3][1]);
    }
    #pragma unroll
    for (int j = 0; j < 4; ++j) {
        size_t ro = (size_t)(nb + j) * 128;
        Y[ro + lane] = acc[j][0];
        Y[ro + lane + 64] = acc[j][1];
    }
}

template<bool RESID, bool G3>
__global__ __launch_bounds__(256, 4) void k_node5(
    const float* __restrict__ X,
    const float* __restrict__ W1, const float* __restrict__ B1,
    const float* __restrict__ W2, const float* __restrict__ B2,
    const float* __restrict__ Hin, float* __restrict__ Hout,
    const float* __restrict__ W3, float* __restrict__ XHout)
{
    __shared__ float tls[4 * 4 * TSTRIDE];   // 8448 B: [wave][node][ch]
    const int w = threadIdx.x >> 6;
    const int lane = threadIdx.x & 63;
    const int nb = __builtin_amdgcn_readfirstlane(blockIdx.x * 16 + w * 4);
    float* tp = &tls[w * 4 * TSTRIDE];
    const float* x0 = X + (size_t)nb * 128;
    const float* x1 = x0 + 128;
    const float* x2 = x1 + 128;
    const float* x3 = x2 + 128;
    // ---- GEMM1: t = ssp(X @ W1 + B1) ----
    float acc1[4][2];
    {
        float ba = B1[lane], bb = B1[lane + 64];
        #pragma unroll
        for (int j = 0; j < 4; ++j) { acc1[j][0] = ba; acc1[j][1] = bb; }
    }
    #pragma unroll 8
    for (int k = 0; k < 128; ++k) {
        float wa = W1[k * 128 + lane];
        float wb = W1[k * 128 + lane + 64];
        float a0 = x0[k], a1 = x1[k], a2 = x2[k], a3 = x3[k];
        acc1[0][0] = fmaf(a0, wa, acc1[0][0]); acc1[0][1] = fmaf(a0, wb, acc1[0][1]);
        acc1[1][0] = fmaf(a1, wa, acc1[1][0]); acc1[1][1] = fmaf(a1, wb, acc1[1][1]);
        acc1[2][0] = fmaf(a2, wa, acc1[2][0]); acc1[2][1] = fmaf(a2, wb, acc1[2][1]);
        acc1[3][0] = fmaf(a3, wa, acc1[3][0]); acc1[3][1] = fmaf(a3, wb, acc1[3][1]);
    }
    #pragma unroll
    for (int j = 0; j < 4; ++j) {
        tp[j * TSTRIDE + lane] = ssp(acc1[j][0]);
        tp[j * TSTRIDE + lane + 64] = ssp(acc1[j][1]);
    }
    __syncthreads();
    // ---- GEMM2: out = t @ W2 + B2 (+Hin) ----
    float acc2[4][2];
    {
        float ba = B2[lane], bb = B2[lane + 64];
        #pragma unroll
        for (int j = 0; j < 4; ++j) { acc2[j][0] = ba; acc2[j][1] = bb; }
    }
    #pragma unroll 4
    for (int k = 0; k < 128; k += 2) {
        float w0a = W2[k * 128 + lane];
        float w0b = W2[k * 128 + lane + 64];
        float w1a = W2[(k + 1) * 128 + lane];
        float w1b = W2[(k + 1) * 128 + lane + 64];
        #pragma unroll
        for (int j = 0; j < 4; ++j) {
            float2 t = *(float2*)&tp[j * TSTRIDE + k];
            acc2[j][0] = fmaf(t.x, w0a, fmaf(t.y, w1a, acc2[j][0]));
            acc2[j][1] = fmaf(t.x, w0b, fmaf(t.y, w1b, acc2[j][1]));
        }
    }
    #pragma unroll
    for (int j = 0; j < 4; ++j) {
        size_t ro = (size_t)(nb + j) * 128;
        if (RESID) {
            acc2[j][0] += Hin[ro + lane];
            acc2[j][1] += Hin[ro + lane + 64];
        }
        Hout[ro + lane] = acc2[j][0];
        Hout[ro + lane + 64] = acc2[j][1];
    }
    // ---- GEMM3: xh_next = out @ W3 ----
    if (G3) {
        __syncthreads();
        #pragma unroll
        for (int j = 0; j < 4; ++j) {
            tp[j * TSTRIDE + lane] = acc2[j][0];
            tp[j * TSTRIDE + lane + 64] = acc2[j][1];
        }
        __syncthreads();
        float acc3[4][2];
        #pragma unroll
        for (int j = 0; j < 4; ++j) { acc3[j][0] = 0.f; acc3[j][1] = 0.f; }
        #pragma unroll 4
        for (int k = 0; k < 128; k += 2) {
            float w0a = W3[k * 128 + lane];
            float w0b = W3[k * 128 + lane + 64];
            float w1a = W3[(k + 1) * 128 + lane];
            float w1b = W3[(k + 1) * 128 + lane + 64];
            #pragma unroll
            for (int j = 0; j < 4; ++j) {
                float2 t = *(float2*)&tp[j * TSTRIDE + k];
                acc3[j][0] = fmaf(t.x, w0a, fmaf(t.y, w1a, acc3[j][0]));
                acc3[j][1] = fmaf(t.x, w0b, fmaf(t.y, w1b, acc3[j][1]));
            }
        }
        #pragma unroll
        for (int j = 0; j < 4; ++j) {
            size_t ro = (size_t)(nb + j) * 128;
            XHout[ro + lane] = acc3[j][0];
            XHout[ro + lane + 64] = acc3[j][1];
        }
    }
}

// Partial-sum pooling using sortedness of batch.
__global__ __launch_bounds__(128) void k_pool2(const float* __restrict__ x,
                                               const int* __restrict__ batch,
                                               float* __restrict__ gsum) {
    const int c = threadIdx.x;
    const int n0 = blockIdx.x * 64;
    float acc = 0.f;
    int cur = batch[n0];
    for (int i = 0; i < 64; ++i) {
        int g = batch[n0 + i];
        float v = x[(size_t)(n0 + i) * 128 + c];
        if (g != cur) {
            atomicAdd(&gsum[cur * 128 + c], acc);
            acc = 0.f;
            cur = g;
        }
        acc += v;
    }
    atomicAdd(&gsum[cur * 128 + c], acc);
}

__global__ void k_div(const float* __restrict__ gsum, const int* __restrict__ batch,
                      float* __restrict__ out) {
    int g = blockIdx.x;
    int c = threadIdx.x;
    int a = 0, b = N_NODES;
    while (a < b) { int m = (a + b) >> 1; if (batch[m] < g) a = m + 1; else b = m; }
    int lo = a;
    b = N_NODES;
    while (a < b) { int m = (a + b) >> 1; if (batch[m] < g + 1) a = m + 1; else b = m; }
    int cnt = a - lo;
    out[g * 128 + c] = gsum[g * 128 + c] / fmaxf((float)cnt, 1.0f);
}

extern "C" void kernel_launch(void* const* d_in, const int* in_sizes, int n_in,
                              void* d_out, int out_size, void* d_ws, size_t ws_size,
                              hipStream_t stream) {
    const int*   z       = (const int*)  d_in[0];
    const float* pos     = (const float*)d_in[1];
    const int*   batch   = (const int*)  d_in[2];
    const int*   ei      = (const int*)  d_in[3];
    const float* emb     = (const float*)d_in[4];
    const float* mlp1_w  = (const float*)d_in[5];
    const float* mlp1_b  = (const float*)d_in[6];
    const float* mlp2_w  = (const float*)d_in[7];
    const float* mlp2_b  = (const float*)d_in[8];
    const float* cl1_w   = (const float*)d_in[9];
    const float* cl2_w   = (const float*)d_in[10];
    const float* cl2_b   = (const float*)d_in[11];
    const float* lin_w   = (const float*)d_in[12];
    const float* lin_b   = (const float*)d_in[13];
    const float* out1_w  = (const float*)d_in[14];
    const float* out1_b  = (const float*)d_in[15];
    const float* out2_w  = (const float*)d_in[16];
    const float* out2_b  = (const float*)d_in[17];

    float* ws     = (float*)d_ws;
    float* h      = ws;
    float* xh     = h    + (size_t)N_NODES * HID;
    float* agg    = xh   + (size_t)N_NODES * HID;
    int2*  meta   = (int2*)(agg + (size_t)N_NODES * HID);
    int*   cnt    = (int*)(meta + N_EDGES);
    int*   rowptr = cnt + N_NODES;
    int*   wo     = rowptr + N_NODES + 1;
    float* gsum   = (float*)(wo + N_NODES);            // 64*128
    float* ftab   = gsum + N_GRAPHS * 128;             // NL*TROWS*FILT floats

    hipMemsetAsync(cnt, 0, N_NODES * sizeof(int), stream);
    hipMemsetAsync(gsum, 0, N_GRAPHS * 128 * sizeof(float), stream);
    k_embed<<<N_NODES * HID / 256, 256, 0, stream>>>(z, emb, h);
    k_hist<<<N_EDGES / 256, 256, 0, stream>>>(ei, cnt);
    k_scan<<<1, 1024, 0, stream>>>(cnt, rowptr, wo);
    k_scatter<<<N_EDGES / 256, 256, 0, stream>>>(ei, pos, wo, meta);
    k_tab<<<NL * 32, 512, 0, stream>>>(mlp1_w, mlp1_b, mlp2_w, mlp2_b, ftab);

    k_gemm0<<<N_NODES / 16, 256, 0, stream>>>(h, cl1_w, xh);
    for (int i = 0; i < NL; ++i) {
        k_edge6<<<N_NODES / 4, 256, 0, stream>>>(
            meta, rowptr, xh, ftab + (size_t)i * TROWS * FILT, agg);
        if (i < NL - 1) {
            k_node5<true, true><<<N_NODES / 16, 256, 0, stream>>>(
                agg, cl2_w + (size_t)i * FILT * HID, cl2_b + (size_t)i * HID,
                lin_w + (size_t)i * HID * HID, lin_b + (size_t)i * HID,
                h, h, cl1_w + (size_t)(i + 1) * HID * FILT, xh);
        } else {
            k_node5<true, false><<<N_NODES / 16, 256, 0, stream>>>(
                agg, cl2_w + (size_t)i * FILT * HID, cl2_b + (size_t)i * HID,
                lin_w + (size_t)i * HID * HID, lin_b + (size_t)i * HID,
                h, h, nullptr, nullptr);
        }
    }
    k_node5<false, false><<<N_NODES / 16, 256, 0, stream>>>(
        h, out1_w, out1_b, out2_w, out2_b, nullptr, xh, nullptr, nullptr);
    k_pool2<<<N_NODES / 64, 128, 0, stream>>>(xh, batch, gsum);
    k_div<<<N_GRAPHS, 128, 0, stream>>>(gsum, batch, (float*)d_out);
}